// Round 11
// baseline (87.356 us; speedup 1.0000x reference)
//
#include <hip/hip_runtime.h>
#include <hip/hip_bf16.h>
#include <math.h>

#define TB 256
#define TILES 4
#define PI_F 3.14159265358979323846f

typedef __attribute__((ext_vector_type(8))) short short8;
typedef __attribute__((ext_vector_type(4))) float f32x4;

union Frag { short8 v; ushort u[8]; uint w[4]; };

__device__ __forceinline__ uint pk2(float a, float b) {
    union { __hip_bfloat162 h; uint u; } cv;
    cv.h = __float22bfloat162_rn(make_float2(a, b));   // packed RNE cvt
    return cv.u;
}

// Wp path (one-time): hi + residual lo
__device__ __forceinline__ void cvt8(const float4& p0, const float4& p1, Frag& hi, Frag& lo) {
    float f[8] = {p0.x, p0.y, p0.z, p0.w, p1.x, p1.y, p1.z, p1.w};
    #pragma unroll
    for (int e = 0; e < 4; ++e) hi.w[e] = pk2(f[2 * e], f[2 * e + 1]);
    #pragma unroll
    for (int e = 0; e < 4; ++e) {
        float r0 = f[2 * e]     - __uint_as_float(hi.w[e] << 16);
        float r1 = f[2 * e + 1] - __uint_as_float(hi.w[e] & 0xffff0000u);
        lo.w[e] = pk2(r0, r1);
    }
}

__device__ __forceinline__ float fast_tanh(float p) {
    float t = __expf(2.0f * p);
    return 1.0f - __fdividef(2.0f, t + 1.0f);
}

__global__ __launch_bounds__(TB, 2) void sqru_fused_kernel(
    const float* __restrict__ x, const float* __restrict__ Wp,
    const float* __restrict__ bp, const float* __restrict__ qw,
    const float* __restrict__ W1, const float* __restrict__ b1,
    const float* __restrict__ W2, const float* __restrict__ b2,
    float* __restrict__ out, int nrows)
{
    __shared__ ushort whi[512 * 8];         // 8 KB Wp hi frags [(s*4+kbi)*16+jc]
    __shared__ ushort wlo[512 * 8];         // 8 KB Wp lo frags
    __shared__ ushort xtile[4][16 * 256];   // 32 KB: per-wave bf16 tile, 16B-XOR swizzled
    __shared__ float  proj_s[4][16 * 17];   // wave-private transpose
    __shared__ float  qbuf[4][16][8];
    __shared__ float  w1_s[32 * 8];
    __shared__ float  w2_s[10 * 32];
    __shared__ float  b1_s[32];
    __shared__ float  b2_s[10];
    __shared__ float  rot_s[8][3][6];

    const int t   = threadIdx.x;
    const int w   = t >> 6;
    const int l   = t & 63;
    const int jc  = l & 15;     // M-row (batch row) and N-col (proj out) index
    const int kbi = l >> 4;     // K sub-group
    const int gw  = blockIdx.x * 4 + w;
    const int tile0 = gw * TILES;

    // ---- prologue: tile0 loaded CONTIGUOUSLY (1KB/instr, full 64B lines) ----
    float4 xr[16];
    {
        #pragma unroll
        for (int i = 0; i < 16; ++i) {
            int rr = tile0 * 16 + i;
            rr = (rr < nrows) ? rr : (nrows - 1);
            xr[i] = *(const float4*)(x + (size_t)rr * 256 + l * 4);
        }
    }

    // ---- one-time weight staging (R9-exact) ----
    if (t < 64) ((float4*)w1_s)[t] = ((const float4*)W1)[t];
    if (t < 80) ((float4*)w2_s)[t] = ((const float4*)W2)[t];
    if (t < 32) b1_s[t] = b1[t];
    if (t < 10) b2_s[t] = b2[t];
    if (t < 24) {
        int u = t / 3, l2 = t % 3;
        float q0 = qw[u * 9 + l2 * 3 + 0];
        float q1 = qw[u * 9 + l2 * 3 + 1];
        float q2 = qw[u * 9 + l2 * 3 + 2];
        rot_s[u][l2][0] = cosf(q0);        rot_s[u][l2][1] = sinf(q0);
        rot_s[u][l2][2] = cosf(0.5f * q1); rot_s[u][l2][3] = sinf(0.5f * q1);
        rot_s[u][l2][4] = cosf(q2);        rot_s[u][l2][5] = sinf(q2);
    }
    #pragma unroll
    for (int ff = 0; ff < 2; ++ff) {
        int f = t + ff * 256;
        int jc2 = f & 15, kb2 = (f >> 4) & 3, s2 = f >> 6;
        const float* wp = Wp + jc2 * 256 + s2 * 32 + kb2 * 8;
        float4 p0 = *(const float4*)wp;
        float4 p1 = *(const float4*)(wp + 4);
        Frag h, lo2;
        cvt8(p0, p1, h, lo2);
        ((short8*)whi)[f] = h.v;
        ((short8*)wlo)[f] = lo2.v;
    }
    __syncthreads();   // only barrier in the kernel

    const float bpj  = bp[jc];
    const int   srow = l >> 2;
    const int   s4   = l & 3;
    const short8* whi_f = (const short8*)whi;
    const short8* wlo_f = (const short8*)wlo;

    char* xw = (char*)&xtile[w][0];                       // write base
    const char* xrd = (const char*)&xtile[w][0] + jc * 512;  // read base (my row)
    const int rdkey = (jc & 7);

    for (int tt = 0; tt < TILES; ++tt) {
        const int tile = tile0 + tt;

        // ---- cvt fp32->bf16 and write wave-private LDS tile (swizzled) ----
        // lane l holds row i's floats [l*4, l*4+4) -> 8B bf16 at chunk c=l>>1, half l&1
        #pragma unroll
        for (int i = 0; i < 16; ++i) {
            uint2 p;
            p.x = pk2(xr[i].x, xr[i].y);
            p.y = pk2(xr[i].z, xr[i].w);
            *(uint2*)(xw + i * 512 + (((l >> 1) ^ (i & 7)) << 4) + ((l & 1) << 3)) = p;
        }

        // ---- reissue contiguous loads for next tile (stays in flight thru epilogue) ----
        if (tt < TILES - 1) {
            #pragma unroll
            for (int i = 0; i < 16; ++i) {
                int rr = (tile + 1) * 16 + i;
                rr = (rr < nrows) ? rr : (nrows - 1);
                xr[i] = *(const float4*)(x + (size_t)rr * 256 + l * 4);
            }
        }

        // ---- MFMA GEMV: 8 K-steps, x-frag from swizzled LDS (1x ds_read_b128) ----
        f32x4 accm = {bpj, bpj, bpj, bpj};
        f32x4 accc = {0.0f, 0.0f, 0.0f, 0.0f};
        #pragma unroll
        for (int s = 0; s < 8; ++s) {
            Frag ah, bh, bl;
            ah.v = *(const short8*)(xrd + (((s * 4 + kbi) ^ rdkey) << 4));
            bh.v = whi_f[(s * 4 + kbi) * 16 + jc];
            bl.v = wlo_f[(s * 4 + kbi) * 16 + jc];
            accm = __builtin_amdgcn_mfma_f32_16x16x32_bf16(ah.v, bh.v, accm, 0, 0, 0);
            accc = __builtin_amdgcn_mfma_f32_16x16x32_bf16(ah.v, bl.v, accc, 0, 0, 0);
        }

        // ---- transpose C[row=kbi*4+r][col=jc] via wave-private LDS ----
        #pragma unroll
        for (int r = 0; r < 4; ++r)
            proj_s[w][(kbi * 4 + r) * 17 + jc] = accm[r] + accc[r];

        float4 pv = *(const float4*)&proj_s[w][srow * 17 + s4 * 4];

        // ---- unit-split circuit: 4 lanes/row, 2 units each ----
        float qv[2];
        #pragma unroll
        for (int uu = 0; uu < 2; ++uu) {
            const int u = 2 * s4 + uu;
            float p0 = (uu == 0) ? pv.x : pv.z;
            float p1 = (uu == 0) ? pv.y : pv.w;
            float th0 = fast_tanh(p0);
            float th1 = fast_tanh(p1);
            float c  = __cosf(0.5f * PI_F * th0);
            float s  = __sinf(0.5f * PI_F * th0);
            float zr = __cosf(PI_F * th1);
            float zi = __sinf(PI_F * th1);

            float ar = c, ai = 0.0f, br = s, bi = 0.0f;
            #pragma unroll
            for (int l2 = 0; l2 < 3; ++l2) {
                if (l2 > 0) {
                    float nar = c * ar - s * br, nai = c * ai - s * bi;
                    float nbr = s * ar + c * br, nbi = s * ai + c * bi;
                    ar = nar; ai = nai; br = nbr; bi = nbi;
                }
                float e0r = rot_s[u][l2][0], e0i = rot_s[u][l2][1];
                float p2r = zr * e0r - zi * e0i;
                float p2q = zr * e0i + zi * e0r;
                float nbr = br * p2r - bi * p2q, nbi = br * p2q + bi * p2r;
                br = nbr; bi = nbi;
                float c1 = rot_s[u][l2][2], s1 = rot_s[u][l2][3];
                float tar = c1 * ar - s1 * br, tai = c1 * ai - s1 * bi;
                float tbr = s1 * ar + c1 * br, tbi = s1 * ai + c1 * bi;
                ar = tar; ai = tai; br = tbr; bi = tbi;
                if (l2 < 2) {
                    float e2r = rot_s[u][l2][4], e2i = rot_s[u][l2][5];
                    float ubr = br * e2r - bi * e2i, ubi = br * e2i + bi * e2r;
                    br = ubr; bi = ubi;
                }
            }
            qv[uu] = (ar * ar + ai * ai) - (br * br + bi * bi);
        }

        float* qb = &qbuf[w][srow][0];
        *(float2*)(qb + 2 * s4) = make_float2(qv[0], qv[1]);
        float4 qa  = *(const float4*)(qb + 0);
        float4 qbv = *(const float4*)(qb + 4);

        // ---- head: lane covers j = s4*8..s4*8+7, 4-lane reduce ----
        float ov[10];
        #pragma unroll
        for (int c2 = 0; c2 < 10; ++c2) ov[c2] = 0.0f;
        #pragma unroll
        for (int jj = 0; jj < 8; ++jj) {
            const int j = s4 * 8 + jj;
            float h = b1_s[j];
            h = fmaf(qa.x,  w1_s[j * 8 + 0], h);
            h = fmaf(qa.y,  w1_s[j * 8 + 1], h);
            h = fmaf(qa.z,  w1_s[j * 8 + 2], h);
            h = fmaf(qa.w,  w1_s[j * 8 + 3], h);
            h = fmaf(qbv.x, w1_s[j * 8 + 4], h);
            h = fmaf(qbv.y, w1_s[j * 8 + 5], h);
            h = fmaf(qbv.z, w1_s[j * 8 + 6], h);
            h = fmaf(qbv.w, w1_s[j * 8 + 7], h);
            h = fmaxf(h, 0.0f);
            #pragma unroll
            for (int c2 = 0; c2 < 10; ++c2) ov[c2] = fmaf(h, w2_s[c2 * 32 + j], ov[c2]);
        }
        #pragma unroll
        for (int c2 = 0; c2 < 10; ++c2) {
            ov[c2] += __shfl_xor(ov[c2], 1);
            ov[c2] += __shfl_xor(ov[c2], 2);
            ov[c2] += b2_s[c2];
        }

        const int orow = tile * 16 + srow;
        if (orow < nrows) {
            float2* op = (float2*)(out + (size_t)orow * 10);
            float lo = (s4 == 0) ? ov[0] : (s4 == 1) ? ov[2] : (s4 == 2) ? ov[4] : ov[6];
            float hi = (s4 == 0) ? ov[1] : (s4 == 1) ? ov[3] : (s4 == 2) ? ov[5] : ov[7];
            op[s4] = make_float2(lo, hi);
            if (s4 == 0) op[4] = make_float2(ov[8], ov[9]);
        }
    }
}

extern "C" void kernel_launch(void* const* d_in, const int* in_sizes, int n_in,
                              void* d_out, int out_size, void* d_ws, size_t ws_size,
                              hipStream_t stream) {
    const float* x  = (const float*)d_in[0];
    const float* Wp = (const float*)d_in[1];
    const float* bp = (const float*)d_in[2];
    const float* qw = (const float*)d_in[3];
    const float* W1 = (const float*)d_in[4];
    const float* b1 = (const float*)d_in[5];
    const float* W2 = (const float*)d_in[6];
    const float* b2 = (const float*)d_in[7];
    float* out = (float*)d_out;

    const int nrows = in_sizes[0] / 256;
    const int rows_per_block = 16 * TILES * 4;   // 256
    const int nblocks = (nrows + rows_per_block - 1) / rows_per_block;
    sqru_fused_kernel<<<nblocks, TB, 0, stream>>>(x, Wp, bp, qw, W1, b1, W2, b2, out, nrows);
}

// Round 12
// 32.264 us; speedup vs baseline: 2.7075x; 2.7075x over previous
//
#include <hip/hip_runtime.h>
#include <hip/hip_bf16.h>
#include <math.h>

#define TB 256
#define TILES 2
#define PI_F 3.14159265358979323846f

typedef __attribute__((ext_vector_type(8))) short short8;
typedef __attribute__((ext_vector_type(4))) float f32x4;

union Frag { short8 v; ushort u[8]; uint w[4]; };

__device__ __forceinline__ uint pk2(float a, float b) {
    union { __hip_bfloat162 h; uint u; } cv;
    cv.h = __float22bfloat162_rn(make_float2(a, b));   // packed RNE cvt
    return cv.u;
}

// x path: hi-only bf16 (4 packed cvts per 8 floats)
__device__ __forceinline__ void cvt_hi(const float4& p0, const float4& p1, Frag& hi) {
    hi.w[0] = pk2(p0.x, p0.y); hi.w[1] = pk2(p0.z, p0.w);
    hi.w[2] = pk2(p1.x, p1.y); hi.w[3] = pk2(p1.z, p1.w);
}

// Wp path (one-time): hi + residual lo
__device__ __forceinline__ void cvt8(const float4& p0, const float4& p1, Frag& hi, Frag& lo) {
    float f[8] = {p0.x, p0.y, p0.z, p0.w, p1.x, p1.y, p1.z, p1.w};
    #pragma unroll
    for (int e = 0; e < 4; ++e) hi.w[e] = pk2(f[2 * e], f[2 * e + 1]);
    #pragma unroll
    for (int e = 0; e < 4; ++e) {
        float r0 = f[2 * e]     - __uint_as_float(hi.w[e] << 16);
        float r1 = f[2 * e + 1] - __uint_as_float(hi.w[e] & 0xffff0000u);
        lo.w[e] = pk2(r0, r1);
    }
}

__device__ __forceinline__ float fast_tanh(float p) {
    float t = __expf(2.0f * p);
    return 1.0f - __fdividef(2.0f, t + 1.0f);
}

__global__ __launch_bounds__(TB, 3) void sqru_fused_kernel(
    const float* __restrict__ x, const float* __restrict__ Wp,
    const float* __restrict__ bp, const float* __restrict__ qw,
    const float* __restrict__ W1, const float* __restrict__ b1,
    const float* __restrict__ W2, const float* __restrict__ b2,
    float* __restrict__ out, int nrows)
{
    __shared__ ushort whi[512 * 8];        // 8 KB Wp hi frags [(s*4+kbi)*16+jc]
    __shared__ ushort wlo[512 * 8];        // 8 KB Wp lo frags
    __shared__ float  proj_s[4][16 * 17];  // wave-private transpose
    __shared__ float  qbuf[4][16][8];
    __shared__ float  w1_s[32 * 8];
    __shared__ float  w2_s[10 * 32];
    __shared__ float  b1_s[32];
    __shared__ float  b2_s[10];
    __shared__ float  rot_s[8][3][6];

    const int t   = threadIdx.x;
    const int w   = t >> 6;
    const int l   = t & 63;
    const int jc  = l & 15;     // M-row (batch row) and N-col (proj out) index
    const int kbi = l >> 4;     // K sub-group
    const int gw  = blockIdx.x * 4 + w;
    const int tile0 = gw * TILES;

    int r0 = tile0 * 16 + jc;       if (r0 >= nrows) r0 = nrows - 1;
    int r1 = (tile0 + 1) * 16 + jc; if (r1 >= nrows) r1 = nrows - 1;
    // FULL-LINE mapping: lane (jc,kbi) reads 16B at row*1KB + s*128 + kbi*16 (and +64)
    // -> 4 kbi-lanes of a row cover one complete 64B line per instruction.
    const float* xp0 = x + (size_t)r0 * 256 + kbi * 4;
    const float* xp1 = x + (size_t)r1 * 256 + kbi * 4;

    // ---- ring prologue: ALL of tile0 (8 K-steps) in flight before staging ----
    float4 xa0 = *(const float4*)(xp0 +   0), xb0 = *(const float4*)(xp0 +  16);
    float4 xa1 = *(const float4*)(xp0 +  32), xb1 = *(const float4*)(xp0 +  48);
    float4 xa2 = *(const float4*)(xp0 +  64), xb2 = *(const float4*)(xp0 +  80);
    float4 xa3 = *(const float4*)(xp0 +  96), xb3 = *(const float4*)(xp0 + 112);
    float4 xa4 = *(const float4*)(xp0 + 128), xb4 = *(const float4*)(xp0 + 144);
    float4 xa5 = *(const float4*)(xp0 + 160), xb5 = *(const float4*)(xp0 + 176);
    float4 xa6 = *(const float4*)(xp0 + 192), xb6 = *(const float4*)(xp0 + 208);
    float4 xa7 = *(const float4*)(xp0 + 224), xb7 = *(const float4*)(xp0 + 240);

    // ---- one-time weight staging (R9-exact trig) ----
    if (t < 64) ((float4*)w1_s)[t] = ((const float4*)W1)[t];
    if (t < 80) ((float4*)w2_s)[t] = ((const float4*)W2)[t];
    if (t < 32) b1_s[t] = b1[t];
    if (t < 10) b2_s[t] = b2[t];
    if (t < 24) {
        int u = t / 3, l2 = t % 3;
        float q0 = qw[u * 9 + l2 * 3 + 0];
        float q1 = qw[u * 9 + l2 * 3 + 1];
        float q2 = qw[u * 9 + l2 * 3 + 2];
        rot_s[u][l2][0] = cosf(q0);        rot_s[u][l2][1] = sinf(q0);
        rot_s[u][l2][2] = cosf(0.5f * q1); rot_s[u][l2][3] = sinf(0.5f * q1);
        rot_s[u][l2][4] = cosf(q2);        rot_s[u][l2][5] = sinf(q2);
    }
    // Wp frags with the SAME permuted element order: e0..3 <- k=kb*4.., e4..7 <- k=16+kb*4..
    #pragma unroll
    for (int ff = 0; ff < 2; ++ff) {
        int f = t + ff * 256;
        int jc2 = f & 15, kb2 = (f >> 4) & 3, s2 = f >> 6;
        const float* wp = Wp + jc2 * 256 + s2 * 32 + kb2 * 4;
        float4 p0 = *(const float4*)wp;
        float4 p1 = *(const float4*)(wp + 16);
        Frag h, lo2;
        cvt8(p0, p1, h, lo2);
        ((short8*)whi)[f] = h.v;
        ((short8*)wlo)[f] = lo2.v;
    }
    __syncthreads();   // only barrier in the kernel

    const float bpj  = bp[jc];
    const int   srow = l >> 2;
    const int   s4   = l & 3;
    const short8* whi_f = (const short8*)whi;
    const short8* wlo_f = (const short8*)wlo;

    auto do_tile = [&](const float* xpn, int tile, bool refill) {
        f32x4 accm = {bpj, bpj, bpj, bpj};
        f32x4 accc = {0.0f, 0.0f, 0.0f, 0.0f};

        // 8 static K-steps; each consumes its slot, then refills it from next tile
        #define STEP(S, XA, XB)                                                     \
        {                                                                           \
            Frag ah; cvt_hi(XA, XB, ah);                                            \
            if (refill) {                                                           \
                XA = *(const float4*)(xpn + (S) * 32);                              \
                XB = *(const float4*)(xpn + (S) * 32 + 16);                         \
            }                                                                       \
            Frag bh, bl;                                                            \
            bh.v = whi_f[((S) * 4 + kbi) * 16 + jc];                                \
            bl.v = wlo_f[((S) * 4 + kbi) * 16 + jc];                                \
            accm = __builtin_amdgcn_mfma_f32_16x16x32_bf16(ah.v, bh.v, accm, 0, 0, 0); \
            accc = __builtin_amdgcn_mfma_f32_16x16x32_bf16(ah.v, bl.v, accc, 0, 0, 0); \
        }
        STEP(0, xa0, xb0)
        STEP(1, xa1, xb1)
        STEP(2, xa2, xb2)
        STEP(3, xa3, xb3)
        STEP(4, xa4, xb4)
        STEP(5, xa5, xb5)
        STEP(6, xa6, xb6)
        STEP(7, xa7, xb7)
        #undef STEP

        // ---- transpose C[row=kbi*4+r][col=jc] via wave-private LDS ----
        #pragma unroll
        for (int r = 0; r < 4; ++r)
            proj_s[w][(kbi * 4 + r) * 17 + jc] = accm[r] + accc[r];

        float4 pv = *(const float4*)&proj_s[w][srow * 17 + s4 * 4];

        // ---- unit-split circuit: 4 lanes/row, 2 units each ----
        float qv[2];
        #pragma unroll
        for (int uu = 0; uu < 2; ++uu) {
            const int u = 2 * s4 + uu;
            float p0 = (uu == 0) ? pv.x : pv.z;
            float p1 = (uu == 0) ? pv.y : pv.w;
            float th0 = fast_tanh(p0);
            float th1 = fast_tanh(p1);
            float c  = __cosf(0.5f * PI_F * th0);
            float s  = __sinf(0.5f * PI_F * th0);
            float zr = __cosf(PI_F * th1);
            float zi = __sinf(PI_F * th1);

            float ar = c, ai = 0.0f, br = s, bi = 0.0f;
            #pragma unroll
            for (int l2 = 0; l2 < 3; ++l2) {
                if (l2 > 0) {
                    float nar = c * ar - s * br, nai = c * ai - s * bi;
                    float nbr = s * ar + c * br, nbi = s * ai + c * bi;
                    ar = nar; ai = nai; br = nbr; bi = nbi;
                }
                float e0r = rot_s[u][l2][0], e0i = rot_s[u][l2][1];
                float p2r = zr * e0r - zi * e0i;
                float p2q = zr * e0i + zi * e0r;
                float nbr = br * p2r - bi * p2q, nbi = br * p2q + bi * p2r;
                br = nbr; bi = nbi;
                float c1 = rot_s[u][l2][2], s1 = rot_s[u][l2][3];
                float tar = c1 * ar - s1 * br, tai = c1 * ai - s1 * bi;
                float tbr = s1 * ar + c1 * br, tbi = s1 * ai + c1 * bi;
                ar = tar; ai = tai; br = tbr; bi = tbi;
                if (l2 < 2) {
                    float e2r = rot_s[u][l2][4], e2i = rot_s[u][l2][5];
                    float ubr = br * e2r - bi * e2i, ubi = br * e2i + bi * e2r;
                    br = ubr; bi = ubi;
                }
            }
            qv[uu] = (ar * ar + ai * ai) - (br * br + bi * bi);
        }

        float* qb = &qbuf[w][srow][0];
        *(float2*)(qb + 2 * s4) = make_float2(qv[0], qv[1]);
        float4 qa  = *(const float4*)(qb + 0);
        float4 qbv = *(const float4*)(qb + 4);

        // ---- head: lane covers j = s4*8..s4*8+7, 4-lane reduce ----
        float ov[10];
        #pragma unroll
        for (int c2 = 0; c2 < 10; ++c2) ov[c2] = 0.0f;
        #pragma unroll
        for (int jj = 0; jj < 8; ++jj) {
            const int j = s4 * 8 + jj;
            float h = b1_s[j];
            h = fmaf(qa.x,  w1_s[j * 8 + 0], h);
            h = fmaf(qa.y,  w1_s[j * 8 + 1], h);
            h = fmaf(qa.z,  w1_s[j * 8 + 2], h);
            h = fmaf(qa.w,  w1_s[j * 8 + 3], h);
            h = fmaf(qbv.x, w1_s[j * 8 + 4], h);
            h = fmaf(qbv.y, w1_s[j * 8 + 5], h);
            h = fmaf(qbv.z, w1_s[j * 8 + 6], h);
            h = fmaf(qbv.w, w1_s[j * 8 + 7], h);
            h = fmaxf(h, 0.0f);
            #pragma unroll
            for (int c2 = 0; c2 < 10; ++c2) ov[c2] = fmaf(h, w2_s[c2 * 32 + j], ov[c2]);
        }
        #pragma unroll
        for (int c2 = 0; c2 < 10; ++c2) {
            ov[c2] += __shfl_xor(ov[c2], 1);
            ov[c2] += __shfl_xor(ov[c2], 2);
            ov[c2] += b2_s[c2];
        }

        const int orow = tile * 16 + srow;
        if (orow < nrows) {
            float2* op = (float2*)(out + (size_t)orow * 10);
            float lo = (s4 == 0) ? ov[0] : (s4 == 1) ? ov[2] : (s4 == 2) ? ov[4] : ov[6];
            float hi = (s4 == 0) ? ov[1] : (s4 == 1) ? ov[3] : (s4 == 2) ? ov[5] : ov[7];
            op[s4] = make_float2(lo, hi);
            if (s4 == 0) op[4] = make_float2(ov[8], ov[9]);
        }
    };

    do_tile(xp1, tile0, true);        // compute tile0, stream in tile1 behind it
    do_tile(xp1, tile0 + 1, false);   // compute tile1, no refill
}

extern "C" void kernel_launch(void* const* d_in, const int* in_sizes, int n_in,
                              void* d_out, int out_size, void* d_ws, size_t ws_size,
                              hipStream_t stream) {
    const float* x  = (const float*)d_in[0];
    const float* Wp = (const float*)d_in[1];
    const float* bp = (const float*)d_in[2];
    const float* qw = (const float*)d_in[3];
    const float* W1 = (const float*)d_in[4];
    const float* b1 = (const float*)d_in[5];
    const float* W2 = (const float*)d_in[6];
    const float* b2 = (const float*)d_in[7];
    float* out = (float*)d_out;

    const int nrows = in_sizes[0] / 256;
    const int rows_per_block = 16 * TILES * 4;   // 128
    const int nblocks = (nrows + rows_per_block - 1) / rows_per_block;
    sqru_fused_kernel<<<nblocks, TB, 0, stream>>>(x, Wp, bp, qw, W1, b1, W2, b2, out, nrows);
}